// Round 3
// baseline (101.656 us; speedup 1.0000x reference)
//
#include <hip/hip_runtime.h>
#include <hip/hip_bf16.h>
#include <math.h>

// Problem constants
#define BATCH   2048
#define TWO_B   4096
#define DIM     1024
#define NBLK4   256           // 16x16 grid of 256x256 tiles
// 1 / (0.07 * ln(2)) : exp(s/T) = exp2(s * INV_T_LOG2E)
#define INV_T_LOG2E 20.60991907f
#define INV_T       14.285714285714286f

typedef float f32x4 __attribute__((ext_vector_type(4)));
typedef long  i64x2 __attribute__((ext_vector_type(2)));

// Scratch in __device__ globals (R14: the 256 MiB d_ws poison fill is
// unconditional, ~43 us/iter serial prelude; only our ~53 us is attackable).
__device__ __attribute__((aligned(4096))) char g_z[(size_t)TWO_B * DIM]; // fp8 e4m3, 4 MB
__device__ float        g_rowsum[TWO_B];
__device__ float        g_positives[TWO_B];
__device__ unsigned int g_counter;

__device__ __forceinline__ void load_lds16(const void* g, void* l) {
    __builtin_amdgcn_global_load_lds(
        (const __attribute__((address_space(1))) void*)g,
        (__attribute__((address_space(3))) void*)l,
        16, 0, 0);
}

// ---------------------------------------------------------------------------
// Kernel 1: L2-normalize 4096 rows -> fp8 e4m3 z[4096][1024] (4 MB).
// Wave-per-row; zero-inits rowsum + completion counter. No fences.
// ---------------------------------------------------------------------------
__global__ __launch_bounds__(256) void normalize_kernel(
        const float* __restrict__ feat) {
    const int lane = threadIdx.x & 63;
    const int row  = blockIdx.x * 4 + (threadIdx.x >> 6);
    if (lane == 0) g_rowsum[row] = 0.0f;
    if (blockIdx.x == 0 && threadIdx.x == 0) g_counter = 0u;

    const float* src = feat + (row < BATCH ? (size_t)row * (2 * DIM)
                                           : (size_t)(row - BATCH) * (2 * DIM) + DIM);
    float4 v[4];
    float ss = 0.0f;
    #pragma unroll
    for (int t = 0; t < 4; ++t) {
        v[t] = ((const float4*)src)[t * 64 + lane];
        ss += v[t].x * v[t].x + v[t].y * v[t].y + v[t].z * v[t].z + v[t].w * v[t].w;
    }
    #pragma unroll
    for (int off = 32; off; off >>= 1) ss += __shfl_xor(ss, off, 64);
    const float scale = 1.0f / fmaxf(sqrtf(ss), 1e-12f);
    int4 o;
    int* op = (int*)&o;
    #pragma unroll
    for (int t = 0; t < 4; ++t) {
        int lo = __builtin_amdgcn_cvt_pk_fp8_f32(v[t].x * scale, v[t].y * scale, 0, false);
        op[t]  = __builtin_amdgcn_cvt_pk_fp8_f32(v[t].z * scale, v[t].w * scale, lo, true);
    }
    ((int4*)(g_z + (size_t)row * DIM))[lane] = o;   // 64 lanes x 16 B = one row
}

// ---------------------------------------------------------------------------
// Kernel 2 (R16 = R15 resubmit, launch_bounds hedge): sim = z z^T, fp8 e4m3,
// m201 8-phase-style schedule. Per K-tile (BK=64): 4 quadrant phases, each
// {6 ds_read_b128 || 1 global_load_lds -> s_barrier -> lgkmcnt(0) ->
// setprio(1) 16 MFMA setprio(0) -> barrier}. 4 LDS K-tile buffers (128 KiB,
// m201-precedented), prefetch depth 3, counted vmcnt(8) per tile (never 0
// in main loop; tail 4 -> 0). Wait derivation: prologue stages tiles 0..2
// (12 loads/wave); each tile issues tile t+3 one-load-per-phase, so at
// phase 3 outstanding <= 12; vmcnt(8) leaves the newest 8 (tiles t+2,t+3)
// => tile t+1 resident. Compute math, XOR swizzles, XCD swizzle, epilogue,
// finalize identical to the R13-proven 2-phase kernel (absmax 0.0).
// ---------------------------------------------------------------------------
__global__ __launch_bounds__(512) void gemm_fused(
        float* __restrict__ out) {
    __shared__ char smem[131072];    // 4 K-tile buffers x 32 KB [sA 16K | sB 16K]

    // XCD-aware swizzle: id&7 = round-robin XCD; 4x8-tile region per XCD
    const int bid = blockIdx.x;
    const int xcd = bid & 7;
    const int t5  = bid >> 3;                   // 0..31 within region
    const int by  = (xcd >> 1) * 4 + (t5 & 3);
    const int bx  = (xcd & 1) * 8 + (t5 >> 2);
    const int rb  = by * 256;
    const int cb  = bx * 256;

    const int tid  = threadIdx.x;
    const int lane = tid & 63;
    const int wv   = tid >> 6;       // wave 0..7
    const int wr   = wv & 3;         // wave row (0..3) -> 64-row subtile
    const int wc   = wv >> 2;        // wave col (0..1) -> 128-col subtile
    const int q    = lane >> 4;      // quad 0..3
    const int mn   = lane & 15;

    f32x4 acc[4][8] = {};

    const int lrow  = lane >> 2;                       // row within 16-row chunk
    const int lsegb = ((lane & 3) ^ ((lane >> 3) & 3)) * 16;   // fetch-side XOR swizzle
    const int rslot = (q ^ ((mn >> 1) & 3)) * 16;      // byte offset in 64-B row

    // staging: 32 chunks of 16 rows x 64 B (A: ci 0..15, B: ci 16..31);
    // wave wv stages ci = 4wv..4wv+3, one chunk per phase.
    size_t goff[4];
    int    loff[4];
    #pragma unroll
    for (int t = 0; t < 4; ++t) {
        const int ci = wv * 4 + t;
        const bool isB = ci >= 16;
        const int  cc  = ci & 15;
        goff[t] = (size_t)((isB ? cb : rb) + cc * 16 + lrow) * DIM + lsegb;
        loff[t] = (isB ? 16384 : 0) + cc * 1024;
    }

    // ---- prologue: stage K-tiles 0..2 into buffers 0..2 (12 loads/wave) ----
    #pragma unroll
    for (int tt = 0; tt < 3; ++tt)
        #pragma unroll
        for (int p = 0; p < 4; ++p)
            load_lds16(g_z + goff[p] + tt * 64, smem + tt * 32768 + loff[p]);
    asm volatile("s_waitcnt vmcnt(8)" ::: "memory");   // tile 0 resident
    __builtin_amdgcn_s_barrier();

    // ---- main loop: 16 K-tiles, 4 phases each ----
    for (int t = 0; t < 16; ++t) {
        const char* cA = smem + (t & 3) * 32768;
        const char* cB = cA + 16384;
        const bool doStage = (t + 3) < 16;
        const int  soff    = (t + 3) * 64;
        char* sdst = smem + ((t + 3) & 3) * 32768;

        #pragma unroll
        for (int p = 0; p < 4; ++p) {
            const int ih = p >> 1;      // A half: i in {2ih, 2ih+1}
            const int jh = p & 1;       // B half: j in {4jh .. 4jh+3}
            i64x2 af[2], bf[4];
            #pragma unroll
            for (int i = 0; i < 2; ++i)
                af[i] = *(const i64x2*)&cA[(wr * 64 + (ih * 2 + i) * 16 + mn) * 64 + rslot];
            #pragma unroll
            for (int j = 0; j < 4; ++j)
                bf[j] = *(const i64x2*)&cB[(wc * 128 + (jh * 4 + j) * 16 + mn) * 64 + rslot];

            if (doStage)
                load_lds16(g_z + goff[p] + soff, sdst + loff[p]);

            if (p == 3) {   // once per K-tile: ensure tile t+1 resident past this barrier
                if (t < 13)       asm volatile("s_waitcnt vmcnt(8)" ::: "memory");
                else if (t == 13) asm volatile("s_waitcnt vmcnt(4)" ::: "memory");
                else if (t == 14) asm volatile("s_waitcnt vmcnt(0)" ::: "memory");
            }
            __builtin_amdgcn_s_barrier();
            asm volatile("s_waitcnt lgkmcnt(0)" ::: "memory");
            __builtin_amdgcn_sched_barrier(0);
            __builtin_amdgcn_s_setprio(1);
            #pragma unroll
            for (int i = 0; i < 2; ++i)
                #pragma unroll
                for (int j = 0; j < 4; ++j) {
                    f32x4& a = acc[ih * 2 + i][jh * 4 + j];
                    a = __builtin_amdgcn_mfma_f32_16x16x32_fp8_fp8(af[i].x, bf[j].x, a, 0, 0, 0);
                    a = __builtin_amdgcn_mfma_f32_16x16x32_fp8_fp8(af[i].y, bf[j].y, a, 0, 0, 0);
                }
            __builtin_amdgcn_s_setprio(0);
            __builtin_amdgcn_s_barrier();
        }
    }

    // ---- Epilogue (shfl; C/D col = lane&15, row = q*4 + reg) ----
    #pragma unroll
    for (int i = 0; i < 4; ++i) {
        #pragma unroll
        for (int reg = 0; reg < 4; ++reg) {
            const int r  = rb + wr * 64 + i * 16 + q * 4 + reg;
            const int pc = (r + BATCH) & (TWO_B - 1);
            float local = 0.0f;
            #pragma unroll
            for (int j = 0; j < 8; ++j) {
                const int c = cb + wc * 128 + j * 16 + mn;
                const float s = acc[i][j][reg];
                if (c == pc)   // unique writer per r
                    __hip_atomic_store(&g_positives[r], s, __ATOMIC_RELAXED,
                                       __HIP_MEMORY_SCOPE_AGENT);
                local += (c == r) ? 0.0f : exp2f(s * INV_T_LOG2E);
            }
            local += __shfl_xor(local, 1, 64);
            local += __shfl_xor(local, 2, 64);
            local += __shfl_xor(local, 4, 64);
            local += __shfl_xor(local, 8, 64);
            if (mn == 0) atomicAdd(&g_rowsum[r], local);
        }
    }

    // ---- fence-free last-block finalize (R7/R8/R13, proven) ----
    __shared__ int amLast;
    __syncthreads();
    if (tid == 0) {
        unsigned int old = __hip_atomic_fetch_add(&g_counter, 1u, __ATOMIC_RELAXED,
                                                  __HIP_MEMORY_SCOPE_AGENT);
        amLast = (old == NBLK4 - 1);
    }
    __syncthreads();
    if (amLast) {
        float acc2 = 0.0f;
        for (int r = tid; r < TWO_B; r += 512) {
            float rs = __hip_atomic_load(&g_rowsum[r], __ATOMIC_RELAXED,
                                         __HIP_MEMORY_SCOPE_AGENT);
            float p  = __hip_atomic_load(&g_positives[r], __ATOMIC_RELAXED,
                                         __HIP_MEMORY_SCOPE_AGENT);
            acc2 += logf(rs) - p * INV_T;
        }
        #pragma unroll
        for (int off = 32; off; off >>= 1) acc2 += __shfl_down(acc2, off, 64);
        __shared__ float s_part[8];
        if ((tid & 63) == 0) s_part[tid >> 6] = acc2;
        __syncthreads();
        if (tid == 0) {
            float tot = 0.0f;
            #pragma unroll
            for (int w = 0; w < 8; ++w) tot += s_part[w];
            out[0] = tot * (1.0f / TWO_B);
        }
    }
}

extern "C" void kernel_launch(void* const* d_in, const int* in_sizes, int n_in,
                              void* d_out, int out_size, void* d_ws, size_t ws_size,
                              hipStream_t stream) {
    const float* feat = (const float*)d_in[0];
    float* out = (float*)d_out;
    (void)d_ws; (void)ws_size;   // poison fill is unconditional (R14) — ws unused

    normalize_kernel<<<TWO_B / 4, 256, 0, stream>>>(feat);
    gemm_fused<<<NBLK4, 512, 0, stream>>>(out);
}

// Round 4
// 91.739 us; speedup vs baseline: 1.1081x; 1.1081x over previous
//
#include <hip/hip_runtime.h>
#include <hip/hip_bf16.h>
#include <math.h>

// Problem constants
#define BATCH   2048
#define TWO_B   4096
#define DIM     1024
#define NBLK4   256           // 16x16 grid of 256x256 tiles
// 1 / (0.07 * ln(2)) : exp(s/T) = exp2(s * INV_T_LOG2E)
#define INV_T_LOG2E 20.60991907f
#define INV_T       14.285714285714286f
#define INV_127SQ   6.200013640958517e-05f   // 1/(127*127)

typedef float f32x4 __attribute__((ext_vector_type(4)));
typedef int   i32x4 __attribute__((ext_vector_type(4)));

// Scratch in __device__ globals (R14: the 256 MiB d_ws poison fill is
// unconditional, ~43 us/iter serial prelude; only our ~53 us is attackable).
// R17: z is now int8 (q = rint(127*z), fixed scale since rows are unit-norm).
__device__ __attribute__((aligned(4096))) char g_z[(size_t)TWO_B * DIM]; // i8, 4 MB
__device__ float        g_rowsum[TWO_B];
__device__ float        g_positives[TWO_B];
__device__ unsigned int g_counter;

__device__ __forceinline__ void load_lds16(const void* g, void* l) {
    __builtin_amdgcn_global_load_lds(
        (const __attribute__((address_space(1))) void*)g,
        (__attribute__((address_space(3))) void*)l,
        16, 0, 0);
}

// ---------------------------------------------------------------------------
// Kernel 1: L2-normalize 4096 rows -> int8 q[4096][1024] (4 MB).
// Wave-per-row; zero-inits rowsum + completion counter. No fences.
// ---------------------------------------------------------------------------
__global__ __launch_bounds__(256) void normalize_kernel(
        const float* __restrict__ feat) {
    const int lane = threadIdx.x & 63;
    const int row  = blockIdx.x * 4 + (threadIdx.x >> 6);
    if (lane == 0) g_rowsum[row] = 0.0f;
    if (blockIdx.x == 0 && threadIdx.x == 0) g_counter = 0u;

    const float* src = feat + (row < BATCH ? (size_t)row * (2 * DIM)
                                           : (size_t)(row - BATCH) * (2 * DIM) + DIM);
    float4 v[4];
    float ss = 0.0f;
    #pragma unroll
    for (int t = 0; t < 4; ++t) {
        v[t] = ((const float4*)src)[t * 64 + lane];
        ss += v[t].x * v[t].x + v[t].y * v[t].y + v[t].z * v[t].z + v[t].w * v[t].w;
    }
    #pragma unroll
    for (int off = 32; off; off >>= 1) ss += __shfl_xor(ss, off, 64);
    const float s127 = 127.0f / fmaxf(sqrtf(ss), 1e-12f);
    int4 o;
    int* op = (int*)&o;
    #pragma unroll
    for (int t = 0; t < 4; ++t) {
        const int b0 = __float2int_rn(v[t].x * s127) & 255;
        const int b1 = __float2int_rn(v[t].y * s127) & 255;
        const int b2 = __float2int_rn(v[t].z * s127) & 255;
        const int b3 = __float2int_rn(v[t].w * s127) & 255;
        op[t] = b0 | (b1 << 8) | (b2 << 16) | (b3 << 24);
    }
    ((int4*)(g_z + (size_t)row * DIM))[lane] = o;   // 64 lanes x 16 B = one row
}

// ---------------------------------------------------------------------------
// Kernel 2 (R17): sim = (q q^T)/127^2 via mfma_i32_16x16x64_i8 — 2x the
// non-scaled fp8 rate (3944 vs 2047 TOPS), K=64/MFMA so each 16-B fragment
// feeds ONE MFMA (half the instruction count). Shell is the R13-proven
// 2-phase structure (R16 showed 8-phase is neutral-to-worse here): 256x256
// tiles, 8 waves, BK=64 dbuf (64 KB LDS), 256 blocks = 1/CU, XOR swizzle
// (staged permutation yields canonical k[16q..16q+16) per lane = exactly
// the i8 K=64 operand layout), XCD 4x8 region swizzle, shfl epilogue,
// fence-free last-block finalize. C/D layout is shape-determined (dtype-
// independent) -> epilogue indexing identical to the fp8 version.
// ---------------------------------------------------------------------------
__global__ __launch_bounds__(512) void gemm_fused(
        float* __restrict__ out) {
    __shared__ char smem[65536];     // buf: [sA 16K | sB 16K] x2

    // XCD-aware swizzle: id&7 = round-robin XCD; 4x8-tile region per XCD
    const int bid = blockIdx.x;
    const int xcd = bid & 7;
    const int t5  = bid >> 3;                   // 0..31 within region
    const int by  = (xcd >> 1) * 4 + (t5 & 3);
    const int bx  = (xcd & 1) * 8 + (t5 >> 2);
    const int rb  = by * 256;
    const int cb  = bx * 256;

    const int tid  = threadIdx.x;
    const int lane = tid & 63;
    const int wv   = tid >> 6;       // wave 0..7
    const int wr   = wv & 3;         // wave row (0..3) -> 64-row subtile
    const int wc   = wv >> 2;        // wave col (0..1) -> 128-col subtile
    const int q    = lane >> 4;      // quad 0..3
    const int mn   = lane & 15;

    i32x4 acc[4][8] = {};            // i32 accumulators (exact)

    const int lrow  = lane >> 2;                       // row within 16-row chunk
    const int lsegb = ((lane & 3) ^ ((lane >> 3) & 3)) * 16;   // fetch-side XOR swizzle
    const int rslot = (q ^ ((mn >> 1) & 3)) * 16;      // byte offset in 64-B row

    // staging: 32 chunks of 16 rows x 64 B (A: ci 0..15, B: ci 16..31);
    // wave wv stages ci = 4wv..4wv+3.
    size_t goff[4];
    int    loff[4];
    #pragma unroll
    for (int t = 0; t < 4; ++t) {
        const int ci = wv * 4 + t;
        const bool isB = ci >= 16;
        const int  cc  = ci & 15;
        goff[t] = (size_t)((isB ? cb : rb) + cc * 16 + lrow) * DIM + lsegb;
        loff[t] = (isB ? 16384 : 0) + cc * 1024;
    }

    // preload K-tile 0 into buffer 0
    #pragma unroll
    for (int t = 0; t < 4; ++t)
        load_lds16(g_z + goff[t], smem + loff[t]);
    __syncthreads();

    int cur = 0;
    for (int k0 = 64; k0 <= DIM; k0 += 64) {
        if (k0 < DIM) {   // prefetch next K-tile into the other buffer
            const int nxt = cur ^ 1;
            #pragma unroll
            for (int t = 0; t < 4; ++t)
                load_lds16(g_z + goff[t] + k0, smem + nxt * 32768 + loff[t]);
        }
        const char* cA = smem + cur * 32768;
        const char* cB = cA + 16384;

        i32x4 af[4], bf[8];
        #pragma unroll
        for (int i = 0; i < 4; ++i)
            af[i] = *(const i32x4*)&cA[(wr * 64 + i * 16 + mn) * 64 + rslot];
        #pragma unroll
        for (int j = 0; j < 8; ++j)
            bf[j] = *(const i32x4*)&cB[(wc * 128 + j * 16 + mn) * 64 + rslot];
        #pragma unroll
        for (int i = 0; i < 4; ++i)
            #pragma unroll
            for (int j = 0; j < 8; ++j)
                acc[i][j] = __builtin_amdgcn_mfma_i32_16x16x64_i8(
                                af[i], bf[j], acc[i][j], 0, 0, 0);
        __syncthreads();
        cur ^= 1;
    }

    // ---- Epilogue (shfl; C/D col = lane&15, row = q*4 + reg) ----
    #pragma unroll
    for (int i = 0; i < 4; ++i) {
        #pragma unroll
        for (int reg = 0; reg < 4; ++reg) {
            const int r  = rb + wr * 64 + i * 16 + q * 4 + reg;
            const int pc = (r + BATCH) & (TWO_B - 1);
            float local = 0.0f;
            #pragma unroll
            for (int j = 0; j < 8; ++j) {
                const int c = cb + wc * 128 + j * 16 + mn;
                const float s = (float)acc[i][j][reg] * INV_127SQ;
                if (c == pc)   // unique writer per r
                    __hip_atomic_store(&g_positives[r], s, __ATOMIC_RELAXED,
                                       __HIP_MEMORY_SCOPE_AGENT);
                local += (c == r) ? 0.0f : exp2f(s * INV_T_LOG2E);
            }
            local += __shfl_xor(local, 1, 64);
            local += __shfl_xor(local, 2, 64);
            local += __shfl_xor(local, 4, 64);
            local += __shfl_xor(local, 8, 64);
            if (mn == 0) atomicAdd(&g_rowsum[r], local);
        }
    }

    // ---- fence-free last-block finalize (R7/R8/R13, proven) ----
    __shared__ int amLast;
    __syncthreads();
    if (tid == 0) {
        unsigned int old = __hip_atomic_fetch_add(&g_counter, 1u, __ATOMIC_RELAXED,
                                                  __HIP_MEMORY_SCOPE_AGENT);
        amLast = (old == NBLK4 - 1);
    }
    __syncthreads();
    if (amLast) {
        float acc2 = 0.0f;
        for (int r = tid; r < TWO_B; r += 512) {
            float rs = __hip_atomic_load(&g_rowsum[r], __ATOMIC_RELAXED,
                                         __HIP_MEMORY_SCOPE_AGENT);
            float p  = __hip_atomic_load(&g_positives[r], __ATOMIC_RELAXED,
                                         __HIP_MEMORY_SCOPE_AGENT);
            acc2 += logf(rs) - p * INV_T;
        }
        #pragma unroll
        for (int off = 32; off; off >>= 1) acc2 += __shfl_down(acc2, off, 64);
        __shared__ float s_part[8];
        if ((tid & 63) == 0) s_part[tid >> 6] = acc2;
        __syncthreads();
        if (tid == 0) {
            float tot = 0.0f;
            #pragma unroll
            for (int w = 0; w < 8; ++w) tot += s_part[w];
            out[0] = tot * (1.0f / TWO_B);
        }
    }
}

extern "C" void kernel_launch(void* const* d_in, const int* in_sizes, int n_in,
                              void* d_out, int out_size, void* d_ws, size_t ws_size,
                              hipStream_t stream) {
    const float* feat = (const float*)d_in[0];
    float* out = (float*)d_out;
    (void)d_ws; (void)ws_size;   // poison fill is unconditional (R14) — ws unused

    normalize_kernel<<<TWO_B / 4, 256, 0, stream>>>(feat);
    gemm_fused<<<NBLK4, 512, 0, stream>>>(out);
}